// Round 12
// baseline (610.934 us; speedup 1.0000x reference)
//
#include <hip/hip_runtime.h>

// ---------------------------------------------------------------------------
// Sparse 3D U-Net forward (MI355X / gfx950).
// All 3x3x3 convs AND strided down-convs = barrier-free implicit GEMM via
// mfma_f32_32x32x16_f16 (2x arithmetic intensity vs 16x16x32):
//   wave = (MG*32) slots x (CTILES*32) couts; A-frag = one 16B gathered
//   load/lane (acts [slot][cin] f16, zero row at cap); B-frag = weights
//   pre-packed to fragment order, loaded directly from global (L1/L2-resident,
//   lane-linear 16B). No LDS, no __syncthreads in conv kernels.
//   A: row=lane&31, k=(lane>>5)*8+j ; B: col=lane&31, same k map (any common
//   k-permutation cancels). D: col=lane&31, row=(reg&3)+8*(reg>>2)+4*(lane>>5).
// Up-convs/cin/final remain f32.
// ---------------------------------------------------------------------------

#define NVOX 100
#define EPSB 1e-4f
typedef unsigned long long u64;
typedef _Float16 h2 __attribute__((ext_vector_type(2)));
typedef _Float16 h8 __attribute__((ext_vector_type(8)));
typedef float f16v __attribute__((ext_vector_type(16)));
#define DEVFN __device__ __forceinline__

// Packed B: wb[((t*CTG + ct)*KCH + kc)*256 + lane*4 + jh] (h2 units):
//   k0 = kc*16 + (lane>>5)*8 + 2*jh ; co = ct*32 + (lane&31)
template<int NTAPS, int CTOT, int COUT>
__global__ __launch_bounds__(256)
void prepB32(const float* __restrict__ w, h2* __restrict__ out)
{
    constexpr int CTG = COUT / 32, KCH = CTOT / 16;
    const int n = NTAPS * CTG * KCH * 256;
    const int idx = blockIdx.x * 256 + threadIdx.x;
    if (idx >= n) return;
    const int jh = idx & 3;
    const int lane = (idx >> 2) & 63;
    int r = idx >> 8;                 // (t*CTG + ct)*KCH + kc
    const int kc = r % KCH; r /= KCH;
    const int ct = r % CTG; const int t = r / CTG;
    const int k0 = kc * 16 + (lane >> 5) * 8 + 2 * jh;
    const int co = ct * 32 + (lane & 31);
    h2 v;
    v[0] = (_Float16)w[((size_t)t * CTOT + k0) * COUT + co];
    v[1] = (_Float16)w[((size_t)t * CTOT + k0 + 1) * COUT + co];
    out[idx] = v;
}

// 3x3x3 SAME submanifold conv, f16 acts, 32x32x16 MFMA, barrier-free.
// grid = (ceil(cap/(128*MG)), COUT/(CTILES*32)); block = 256 (4 waves).
template<int KC1, int KC2, int MG, int CTILES, int COUT, int S>
__global__ __launch_bounds__(256)
void gconv_m32(const h2* __restrict__ inA, const h2* __restrict__ inB,
               const h2* __restrict__ wb,
               const int* __restrict__ amap, const int* __restrict__ vlist,
               const int* __restrict__ cnt, int cap, float* __restrict__ out)
{
    constexpr int KCH = KC1 + KC2;
    constexpr int CTG = COUT / 32;
    const int tid = threadIdx.x, lane = tid & 63, wid = tid >> 6;
    const int cntv = *cnt;
    constexpr int BLK = 4 * MG * 32;
    if (blockIdx.x * BLK >= cntv) return;
    const int wbase = blockIdx.x * BLK + wid * MG * 32;
    const int ct0 = blockIdx.y * CTILES;
    const int l31 = lane & 31, ksub = lane >> 5;
    int X[MG], Y[MG], Z[MG];
    bool on[MG];
#pragma unroll
    for (int mg = 0; mg < MG; ++mg) {
        const int slot = wbase + mg * 32 + l31;
        on[mg] = slot < cntv;
        X[mg] = 0; Y[mg] = 0; Z[mg] = 0;
        if (on[mg]) { const int v = vlist[slot]; X[mg] = v % S; const int r = v / S; Y[mg] = r % S; Z[mg] = r / S; }
    }
    auto calc = [&](int t, int (&ns)[MG]) {
        const int dz = t / 9 - 1, dy = (t / 3) % 3 - 1, dx = t % 3 - 1;
#pragma unroll
        for (int mg = 0; mg < MG; ++mg) {
            int n = cap;
            if (on[mg]) {
                const int nz = Z[mg] + dz, ny = Y[mg] + dy, nx = X[mg] + dx;
                if ((unsigned)nz < (unsigned)S && (unsigned)ny < (unsigned)S &&
                    (unsigned)nx < (unsigned)S) {
                    const int m = amap[(nz * S + ny) * S + nx];
                    if (m >= 0) n = m;
                }
            }
            ns[mg] = n;
        }
    };

    f16v acc[MG][CTILES];
#pragma unroll
    for (int mg = 0; mg < MG; ++mg)
#pragma unroll
        for (int c = 0; c < CTILES; ++c) acc[mg][c] = (f16v)(0.f);

    int ns[MG];
    calc(0, ns);
#pragma unroll 1
    for (int t = 0; t < 27; ++t) {
        int nsn[MG];
        if (t + 1 < 27) calc(t + 1, nsn);
        else {
#pragma unroll
            for (int mg = 0; mg < MG; ++mg) nsn[mg] = cap;
        }
        const h2* __restrict__ wt = wb + ((size_t)t * CTG + ct0) * KCH * 256;
#pragma unroll
        for (int kc = 0; kc < KC1; ++kc) {
            h8 a[MG];
#pragma unroll
            for (int mg = 0; mg < MG; ++mg)
                a[mg] = *reinterpret_cast<const h8*>(
                    inA + (size_t)ns[mg] * (KC1 * 8) + kc * 8 + ksub * 4);
#pragma unroll
            for (int ct = 0; ct < CTILES; ++ct) {
                const h8 b = *reinterpret_cast<const h8*>(
                    wt + ((size_t)ct * KCH + kc) * 256 + lane * 4);
#pragma unroll
                for (int mg = 0; mg < MG; ++mg)
                    acc[mg][ct] = __builtin_amdgcn_mfma_f32_32x32x16_f16(
                        a[mg], b, acc[mg][ct], 0, 0, 0);
            }
        }
        if constexpr (KC2 > 0) {
#pragma unroll
            for (int kc = 0; kc < KC2; ++kc) {
                h8 a[MG];
#pragma unroll
                for (int mg = 0; mg < MG; ++mg)
                    a[mg] = *reinterpret_cast<const h8*>(
                        inB + (size_t)ns[mg] * (KC2 * 8) + kc * 8 + ksub * 4);
#pragma unroll
                for (int ct = 0; ct < CTILES; ++ct) {
                    const h8 b = *reinterpret_cast<const h8*>(
                        wt + ((size_t)ct * KCH + KC1 + kc) * 256 + lane * 4);
#pragma unroll
                    for (int mg = 0; mg < MG; ++mg)
                        acc[mg][ct] = __builtin_amdgcn_mfma_f32_32x32x16_f16(
                            a[mg], b, acc[mg][ct], 0, 0, 0);
                }
            }
        }
#pragma unroll
        for (int mg = 0; mg < MG; ++mg) ns[mg] = nsn[mg];
    }
    // D: col=l31, row=(r&3)+8*(r>>2)+4*ksub
#pragma unroll
    for (int mg = 0; mg < MG; ++mg)
#pragma unroll
        for (int ct = 0; ct < CTILES; ++ct)
#pragma unroll
            for (int r = 0; r < 16; ++r) {
                const int row = (r & 3) + 8 * (r >> 2) + 4 * ksub;
                const int srow = wbase + mg * 32 + row;
                if (srow < cntv)
                    out[(size_t)srow * COUT + (ct0 + ct) * 32 + l31] = acc[mg][ct][r];
            }
}

// 2x2x2 stride-2 down conv, coarse-driven, f16 acts, 32x32x16 MFMA.
template<int KCH, int MG, int CTILES, int COUT, int SC>
__global__ __launch_bounds__(256)
void dconv_m32(const h2* __restrict__ in, const h2* __restrict__ wb,
               const int* __restrict__ amap_f, const int* __restrict__ vlist_c,
               const int* __restrict__ cnt_c, int capf, float* __restrict__ out)
{
    constexpr int SF = SC * 2;
    constexpr int CTG = COUT / 32;
    const int tid = threadIdx.x, lane = tid & 63, wid = tid >> 6;
    const int cntv = *cnt_c;
    constexpr int BLK = 4 * MG * 32;
    if (blockIdx.x * BLK >= cntv) return;
    const int wbase = blockIdx.x * BLK + wid * MG * 32;
    const int ct0 = blockIdx.y * CTILES;
    const int l31 = lane & 31, ksub = lane >> 5;
    int X[MG], Y[MG], Z[MG];
    bool on[MG];
#pragma unroll
    for (int mg = 0; mg < MG; ++mg) {
        const int slot = wbase + mg * 32 + l31;
        on[mg] = slot < cntv;
        X[mg] = 0; Y[mg] = 0; Z[mg] = 0;
        if (on[mg]) { const int v = vlist_c[slot]; X[mg] = v % SC; const int r = v / SC; Y[mg] = r % SC; Z[mg] = r / SC; }
    }
    auto calc = [&](int t, int (&ns)[MG]) {
#pragma unroll
        for (int mg = 0; mg < MG; ++mg) {
            int n = capf;
            if (on[mg]) {
                const int fz = 2 * Z[mg] + ((t >> 2) & 1);
                const int fy = 2 * Y[mg] + ((t >> 1) & 1);
                const int fx = 2 * X[mg] + (t & 1);
                const int m = amap_f[(fz * SF + fy) * SF + fx];
                if (m >= 0) n = m;
            }
            ns[mg] = n;
        }
    };

    f16v acc[MG][CTILES];
#pragma unroll
    for (int mg = 0; mg < MG; ++mg)
#pragma unroll
        for (int c = 0; c < CTILES; ++c) acc[mg][c] = (f16v)(0.f);

    int ns[MG];
    calc(0, ns);
#pragma unroll 1
    for (int t = 0; t < 8; ++t) {
        int nsn[MG];
        if (t + 1 < 8) calc(t + 1, nsn);
        else {
#pragma unroll
            for (int mg = 0; mg < MG; ++mg) nsn[mg] = capf;
        }
        const h2* __restrict__ wt = wb + ((size_t)t * CTG + ct0) * KCH * 256;
#pragma unroll
        for (int kc = 0; kc < KCH; ++kc) {
            h8 a[MG];
#pragma unroll
            for (int mg = 0; mg < MG; ++mg)
                a[mg] = *reinterpret_cast<const h8*>(
                    in + (size_t)ns[mg] * (KCH * 8) + kc * 8 + ksub * 4);
#pragma unroll
            for (int ct = 0; ct < CTILES; ++ct) {
                const h8 b = *reinterpret_cast<const h8*>(
                    wt + ((size_t)ct * KCH + kc) * 256 + lane * 4);
#pragma unroll
                for (int mg = 0; mg < MG; ++mg)
                    acc[mg][ct] = __builtin_amdgcn_mfma_f32_32x32x16_f16(
                        a[mg], b, acc[mg][ct], 0, 0, 0);
            }
        }
#pragma unroll
        for (int mg = 0; mg < MG; ++mg) ns[mg] = nsn[mg];
    }
#pragma unroll
    for (int mg = 0; mg < MG; ++mg)
#pragma unroll
        for (int ct = 0; ct < CTILES; ++ct)
#pragma unroll
            for (int r = 0; r < 16; ++r) {
                const int row = (r & 3) + 8 * (r >> 2) + 4 * ksub;
                const int srow = wbase + mg * 32 + row;
                if (srow < cntv)
                    out[(size_t)srow * COUT + (ct0 + ct) * 32 + l31] = acc[mg][ct][r];
            }
}

// Fused bnrelu + f32->f16 pack: dst[slot][C/2 h2] over cnt*C floats (C%8==0).
__global__ __launch_bounds__(256)
void act_h16(const float* __restrict__ src, h2* __restrict__ dst,
             const float* __restrict__ sc, const float* __restrict__ sh,
             const int* __restrict__ cnt, int C)
{
    const int f = (blockIdx.x * 256 + threadIdx.x) * 8;
    if (f >= (*cnt) * C) return;
    const int c0 = f % C;
    const float4 v0 = *reinterpret_cast<const float4*>(src + f);
    const float4 v1 = *reinterpret_cast<const float4*>(src + f + 4);
    const float r[8] = {
        fmaxf(fmaf(v0.x, sc[c0 + 0], sh[c0 + 0]), 0.f),
        fmaxf(fmaf(v0.y, sc[c0 + 1], sh[c0 + 1]), 0.f),
        fmaxf(fmaf(v0.z, sc[c0 + 2], sh[c0 + 2]), 0.f),
        fmaxf(fmaf(v0.w, sc[c0 + 3], sh[c0 + 3]), 0.f),
        fmaxf(fmaf(v1.x, sc[c0 + 4], sh[c0 + 4]), 0.f),
        fmaxf(fmaf(v1.y, sc[c0 + 5], sh[c0 + 5]), 0.f),
        fmaxf(fmaf(v1.z, sc[c0 + 6], sh[c0 + 6]), 0.f),
        fmaxf(fmaf(v1.w, sc[c0 + 7], sh[c0 + 7]), 0.f)};
    union { float4 v; h2 h[4]; } o;
#pragma unroll
    for (int k = 0; k < 4; ++k) {
        h2 p; p[0] = (_Float16)r[2 * k]; p[1] = (_Float16)r[2 * k + 1];
        o.h[k] = p;
    }
    *reinterpret_cast<float4*>(dst + f / 2) = o.v;
}

// ---------------- f32 machinery for up convs (LDS-staged, R6) ----------------

template<int CTOT, int COUT>
DEVFN void stage_tap(const float* __restrict__ wtap, int cg32,
                     float* __restrict__ lbuf, int wid, int lane)
{
    constexpr int IPW = CTOT / 32;
#pragma unroll
    for (int i = 0; i < IPW; ++i) {
        const int chunk = wid * IPW + i;
        const int f4i = chunk * 64 + lane;
        const int ci = f4i >> 3, sub = f4i & 7;
        const float* g = wtap + ci * COUT + cg32 + sub * 4;
        __builtin_amdgcn_global_load_lds(
            (const __attribute__((address_space(1))) void*)g,
            (__attribute__((address_space(3))) void*)(lbuf + chunk * 256),
            16, 0, 0);
    }
}

template<int CIN>
DEVFN void dorow8(const float* __restrict__ row, const float* __restrict__ wl,
                  float (&acc)[8])
{
#pragma unroll 4
    for (int c0 = 0; c0 < CIN; c0 += 4) {
        const float4 a = *reinterpret_cast<const float4*>(row + c0);
        const float av[4] = {a.x, a.y, a.z, a.w};
#pragma unroll
        for (int j = 0; j < 4; ++j) {
            const float4 w0 = *reinterpret_cast<const float4*>(wl + (c0 + j) * 32);
            const float4 w1 = *reinterpret_cast<const float4*>(wl + (c0 + j) * 32 + 4);
            acc[0] = fmaf(av[j], w0.x, acc[0]);
            acc[1] = fmaf(av[j], w0.y, acc[1]);
            acc[2] = fmaf(av[j], w0.z, acc[2]);
            acc[3] = fmaf(av[j], w0.w, acc[3]);
            acc[4] = fmaf(av[j], w1.x, acc[4]);
            acc[5] = fmaf(av[j], w1.y, acc[5]);
            acc[6] = fmaf(av[j], w1.z, acc[6]);
            acc[7] = fmaf(av[j], w1.w, acc[7]);
        }
    }
}

template<int CIN, int COUT, int SC>
__global__ __launch_bounds__(256)
void uconv_w(const float* __restrict__ in, const float* __restrict__ w,
             const int* __restrict__ amap_f, const int* __restrict__ vlist_c,
             const int* __restrict__ cnt_c, float* __restrict__ out)
{
    constexpr int SF = SC * 2;
    __shared__ float lw[2][CIN * 32];
    const int tid = threadIdx.x, lane = tid & 63, wid = tid >> 6;
    const int cntv = *cnt_c;
    if (blockIdx.x * 64 >= cntv) return;
    const int slot = blockIdx.x * 64 + lane;
    const int cg32 = blockIdx.y * 32;
    const bool on = slot < cntv;
    int X = 0, Y = 0, Z = 0;
    if (on) { const int v = vlist_c[slot]; X = v % SC; const int r = v / SC; Y = r % SC; Z = r / SC; }
    stage_tap<CIN, COUT>(w + (size_t)7 * CIN * COUT, cg32, lw[0], wid, lane);
    __syncthreads();
#pragma unroll 1
    for (int t = 0; t < 8; ++t) {
        if (t + 1 < 8)
            stage_tap<CIN, COUT>(w + (size_t)(6 - t) * CIN * COUT, cg32,
                                 lw[(t + 1) & 1], wid, lane);
        int cs = -1;
        if (on) {
            const int fz = 2 * Z + ((t >> 2) & 1);
            const int fy = 2 * Y + ((t >> 1) & 1);
            const int fx = 2 * X + (t & 1);
            cs = amap_f[(fz * SF + fy) * SF + fx];
        }
        if (cs >= 0) {
            float acc[8];
#pragma unroll
            for (int q = 0; q < 8; ++q) acc[q] = 0.f;
            dorow8<CIN>(in + (size_t)slot * CIN, &lw[t & 1][wid * 8], acc);
            float* __restrict__ op = out + (size_t)cs * COUT + cg32 + wid * 8;
            *reinterpret_cast<float4*>(op) = make_float4(acc[0], acc[1], acc[2], acc[3]);
            *reinterpret_cast<float4*>(op + 4) = make_float4(acc[4], acc[5], acc[6], acc[7]);
        }
        __syncthreads();
    }
}

// First conv: dense 1-channel grid -> 32ch sparse.
template<int OSPLIT, int S>
__global__ __launch_bounds__(64 * OSPLIT)
void cin_k(const float* __restrict__ grid, const float* __restrict__ w,
           const int* __restrict__ vlist, const int* __restrict__ cnt,
           float* __restrict__ out)
{
    constexpr int OW = 32 / OSPLIT;
    const int wOff = __builtin_amdgcn_readfirstlane(threadIdx.x >> 6) * OW;
    const int slot = blockIdx.x * 64 + (threadIdx.x & 63);
    if (slot >= *cnt) return;
    const int v = vlist[slot];
    const int x = v % S;
    const int rem = v / S;
    const int y = rem % S;
    const int z = rem / S;
    float acc[OW];
#pragma unroll
    for (int c = 0; c < OW; ++c) acc[c] = 0.f;
#pragma unroll
    for (int t = 0; t < 27; ++t) {
        const int dz = t / 9 - 1, dy = (t / 3) % 3 - 1, dx = t % 3 - 1;
        const int nz = z + dz, ny = y + dy, nx = x + dx;
        if ((unsigned)nz >= (unsigned)S || (unsigned)ny >= (unsigned)S ||
            (unsigned)nx >= (unsigned)S) continue;
        const float val = grid[(nz * S + ny) * S + nx];
        const float* __restrict__ wp = w + t * 32 + wOff;
#pragma unroll
        for (int c = 0; c < OW; ++c) acc[c] = fmaf(val, wp[c], acc[c]);
    }
    float* __restrict__ op = out + (size_t)slot * 32 + wOff;
#pragma unroll
    for (int c = 0; c < OW; ++c) op[c] = acc[c];
}

// Elementwise bnrelu (f32 out).
__global__ __launch_bounds__(256)
void act_k(const float* __restrict__ src, float* __restrict__ dst,
           const float* __restrict__ sc, const float* __restrict__ sh,
           const int* __restrict__ cnt, int C)
{
    const int f = (blockIdx.x * 256 + threadIdx.x) * 4;
    if (f >= (*cnt) * C) return;
    const int c0 = f % C;
    const float4 v = *reinterpret_cast<const float4*>(src + f);
    float4 o;
    o.x = fmaxf(fmaf(v.x, sc[c0 + 0], sh[c0 + 0]), 0.f);
    o.y = fmaxf(fmaf(v.y, sc[c0 + 1], sh[c0 + 1]), 0.f);
    o.z = fmaxf(fmaf(v.z, sc[c0 + 2], sh[c0 + 2]), 0.f);
    o.w = fmaxf(fmaf(v.w, sc[c0 + 3], sh[c0 + 3]), 0.f);
    *reinterpret_cast<float4*>(dst + f) = o;
}

// Final: bnrelu(y0, bnJ) then 32->3 linear per point.
__global__ __launch_bounds__(256)
void final_k(const int* __restrict__ coords, const float* __restrict__ y0,
             const int* __restrict__ amap0, const float* __restrict__ ssJ,
             const float* __restrict__ linW, const float* __restrict__ linb,
             int N, float* __restrict__ outp)
{
    const int n = blockIdx.x * blockDim.x + threadIdx.x;
    if (n >= N) return;
    const int i = coords[3 * n + 0];
    const int j = coords[3 * n + 1];
    const int k = coords[3 * n + 2];
    const int v = (i * NVOX + j) * NVOX + k;
    const int s = amap0[v];
    float a0 = linb[0], a1 = linb[1], a2 = linb[2];
    if (s >= 0) {
        const float* __restrict__ row = y0 + (size_t)s * 32;
#pragma unroll
        for (int c = 0; c < 32; ++c) {
            const float t = fmaxf(fmaf(row[c], ssJ[c], ssJ[32 + c]), 0.f);
            a0 = fmaf(t, linW[c * 3 + 0], a0);
            a1 = fmaf(t, linW[c * 3 + 1], a1);
            a2 = fmaf(t, linW[c * 3 + 2], a2);
        }
    }
    outp[3 * n + 0] = a0;
    outp[3 * n + 1] = a1;
    outp[3 * n + 2] = a2;
}

// Precompute per-channel scale/shift for all 10 BN layers.
__global__ void bn_prep(const float* __restrict__ A, const float* __restrict__ B,
                        const float* __restrict__ C, const float* __restrict__ D,
                        const float* __restrict__ E, const float* __restrict__ F,
                        const float* __restrict__ G, const float* __restrict__ H,
                        const float* __restrict__ I, const float* __restrict__ J,
                        float* __restrict__ ss)
{
    const float* bp[10] = {A, B, C, D, E, F, G, H, I, J};
    const int CH[10] = {32, 32, 64, 64, 96, 96, 128, 64, 64, 32};
    int idx = blockIdx.x * blockDim.x + threadIdx.x;
    if (idx >= 672) return;
    int l = 0, base = 0, off2 = 0;
    while (idx >= base + CH[l]) { base += CH[l]; off2 += 2 * CH[l]; ++l; }
    const int c = idx - base;
    const float* bn = bp[l];
    const int Cc = CH[l];
    const float g = bn[c], b = bn[Cc + c], mu = bn[2 * Cc + c], var = bn[3 * Cc + c];
    const float sc = g * rsqrtf(var + EPSB);
    ss[off2 + c] = sc;
    ss[off2 + Cc + c] = b - mu * sc;
}

__global__ __launch_bounds__(256)
void scatter_mark(const int* __restrict__ coords, const float* __restrict__ feats,
                  int N, float* __restrict__ grid, int* __restrict__ amap0)
{
    const int n = blockIdx.x * blockDim.x + threadIdx.x;
    if (n >= N) return;
    const int i = coords[3 * n + 0];
    const int j = coords[3 * n + 1];
    const int k = coords[3 * n + 2];
    const int v = (i * NVOX + j) * NVOX + k;
    atomicAdd(&grid[v], feats[n]);
    amap0[v] = -2;
}

template<int SC>
__global__ __launch_bounds__(256)
void flag_coarse(const int* __restrict__ amap_f, int* __restrict__ amap_c)
{
    constexpr int SF = SC * 2;
    const int v = blockIdx.x * blockDim.x + threadIdx.x;
    if (v >= SC * SC * SC) return;
    const int x = v % SC;
    const int rem = v / SC;
    const int y = rem % SC;
    const int z = rem / SC;
    bool any = false;
#pragma unroll
    for (int t = 0; t < 8; ++t) {
        const int fz = 2 * z + ((t >> 2) & 1);
        const int fy = 2 * y + ((t >> 1) & 1);
        const int fx = 2 * x + (t & 1);
        if (amap_f[(fz * SF + fy) * SF + fx] >= 0) any = true;
    }
    amap_c[v] = any ? -2 : -1;
}

// ---- deterministic raster-order compaction: count -> scan -> emit ----
__global__ __launch_bounds__(256)
void count_k(const int* __restrict__ flags, int V, int* __restrict__ counts)
{
    const int v = blockIdx.x * 256 + threadIdx.x;
    const bool act = (v < V) && (flags[v] == -2);
    const u64 m = __ballot(act);
    __shared__ int c[4];
    const int wid = threadIdx.x >> 6;
    if ((threadIdx.x & 63) == 0) c[wid] = __popcll(m);
    __syncthreads();
    if (threadIdx.x == 0) counts[blockIdx.x] = c[0] + c[1] + c[2] + c[3];
}

__global__ __launch_bounds__(1024)
void scan_k(int* __restrict__ counts, int nb, int* __restrict__ total)
{
    __shared__ int sums[1024];
    const int t = threadIdx.x;
    int v[4];
    int s = 0;
#pragma unroll
    for (int i = 0; i < 4; ++i) {
        const int idx = t * 4 + i;
        v[i] = (idx < nb) ? counts[idx] : 0;
        s += v[i];
    }
    sums[t] = s;
    __syncthreads();
    for (int d = 1; d < 1024; d <<= 1) {
        const int add = (t >= d) ? sums[t - d] : 0;
        __syncthreads();
        sums[t] += add;
        __syncthreads();
    }
    int base = (t > 0) ? sums[t - 1] : 0;
#pragma unroll
    for (int i = 0; i < 4; ++i) {
        const int idx = t * 4 + i;
        if (idx < nb) counts[idx] = base;
        base += v[i];
    }
    if (t == 1023) *total = sums[1023];
}

__global__ __launch_bounds__(256)
void emit_k(int* __restrict__ amap, int V, const int* __restrict__ offsets,
            int* __restrict__ vlist)
{
    const int v = blockIdx.x * 256 + threadIdx.x;
    const bool act = (v < V) && (amap[v] == -2);
    const u64 m = __ballot(act);
    __shared__ int wbase[4];
    const int wid = threadIdx.x >> 6;
    const int lane = threadIdx.x & 63;
    if (lane == 0) wbase[wid] = __popcll(m);
    __syncthreads();
    if (threadIdx.x == 0) {
        int s = 0;
#pragma unroll
        for (int i = 0; i < 4; ++i) { const int t = wbase[i]; wbase[i] = s; s += t; }
    }
    __syncthreads();
    if (act) {
        const int slot = offsets[blockIdx.x] + wbase[wid] +
                         __popcll(m & ((1ull << lane) - 1ull));
        amap[v] = slot;
        vlist[slot] = v;
    }
}

extern "C" void kernel_launch(void* const* d_in, const int* in_sizes, int n_in,
                              void* d_out, int out_size, void* d_ws, size_t ws_size,
                              hipStream_t stream) {
    const int*   coords = (const int*)d_in[0];
    const float* feats  = (const float*)d_in[1];
    const float* w_in   = (const float*)d_in[2];
    const float* w0a    = (const float*)d_in[3];
    const float* wdown0 = (const float*)d_in[4];
    const float* w1a    = (const float*)d_in[5];
    const float* wdown1 = (const float*)d_in[6];
    const float* w2     = (const float*)d_in[7];
    const float* wup1   = (const float*)d_in[8];
    const float* w1post = (const float*)d_in[9];
    const float* wup0   = (const float*)d_in[10];
    const float* w0post = (const float*)d_in[11];
    const float* linW = (const float*)d_in[22];
    const float* linb = (const float*)d_in[23];
    float* outp = (float*)d_out;

    const int N = in_sizes[1];            // 120000 points
    const int V0 = NVOX * NVOX * NVOX;
    const int V1 = 50 * 50 * 50;
    const int V2 = 25 * 25 * 25;
    const int cap0 = N;
    const int cap1 = 100000;
    const int cap2 = V2;

    char* ws = (char*)d_ws;
    size_t off = 0;
    auto alloc = [&](size_t bytes) -> void* {
        void* p = ws + off;
        off += (bytes + 255) & ~(size_t)255;
        return p;
    };
    int*   amap0  = (int*)alloc((size_t)V0 * 4);
    int*   vlist0 = (int*)alloc((size_t)cap0 * 4);
    int*   amap1  = (int*)alloc((size_t)V1 * 4);
    int*   vlist1 = (int*)alloc((size_t)cap1 * 4);
    int*   amap2  = (int*)alloc((size_t)V2 * 4);
    int*   vlist2 = (int*)alloc((size_t)cap2 * 4);
    int*   cnt    = (int*)alloc(3 * 4);
    int*   counts = (int*)alloc(4096 * 4);
    float* ss     = (float*)alloc(1344 * 4);
    float* grid   = (float*)alloc((size_t)V0 * 4);
    float* P1 = (float*)alloc((size_t)cap0 * 32 * 4);  // x -> HG2 -> u0
    float* P2 = (float*)alloc((size_t)cap0 * 32 * 4);  // x0 -> y0
    float* P3 = (float*)alloc((size_t)cap0 * 32 * 4);  // HA / HB / HI1
    float* Q1 = (float*)alloc((size_t)cap1 * 64 * 4);  // d0 -> HE -> u1
    float* Q2 = (float*)alloc((size_t)cap1 * 64 * 4);  // x1 -> y1/actH -> HI2
    float* Q3 = (float*)alloc((size_t)cap1 * 64 * 4);  // HC / HD / HG1
    float* R1 = (float*)alloc((size_t)cap2 * 96 * 4);  // d1
    float* R2 = (float*)alloc((size_t)cap2 * 96 * 4);  // x2/actF
    h2* wbA  = (h2*)alloc((size_t)27 * 1 * 2 * 256 * 4);   // w0a packed B32
    h2* wb1  = (h2*)alloc((size_t)27 * 2 * 4 * 256 * 4);   // w1a
    h2* wb2  = (h2*)alloc((size_t)27 * 3 * 6 * 256 * 4);   // w2
    h2* wbP1 = (h2*)alloc((size_t)27 * 2 * 8 * 256 * 4);   // w1post
    h2* wbP0 = (h2*)alloc((size_t)27 * 1 * 4 * 256 * 4);   // w0post
    h2* wbD0 = (h2*)alloc((size_t)8 * 2 * 2 * 256 * 4);    // wdown0
    h2* wbD1 = (h2*)alloc((size_t)8 * 3 * 4 * 256 * 4);    // wdown1
    if (off > ws_size) return;

    // f16 activation aliases (sequentially reused dead f32 buffers)
    h2* HA  = (h2*)P3;   // actA  (16 h2/row)
    h2* HB  = (h2*)P3;   // actB  (16) — reuses HA geometry + zero row
    h2* HC  = (h2*)Q3;   // actC  (32)
    h2* HD  = (h2*)Q3;   // actD  (32) — reuses HC geometry + zero row
    h2* HE  = (h2*)Q1;   // actE  (48)
    h2* HG1 = (h2*)Q3;   // actG1 (32)
    h2* HG2 = (h2*)P1;   // actG2 (32)
    h2* HI1 = (h2*)P3;   // actI1 (16)
    h2* HI2 = (h2*)Q2;   // actI2 (16)

    const int B = 256;
    const int gN  = (N + B - 1) / B;
    const int nb0 = (V0 + B - 1) / B;
    const int nb1 = (V1 + B - 1) / B;
    const int nb2 = (V2 + B - 1) / B;
    const int gA64 = (cap1 * 64 / 4 + 255) / 256;
    const int gA96 = (cap2 * 96 / 4 + 255) / 256;
    const int gH32_0 = (cap0 * 32 / 8 + 255) / 256;
    const int gH64_1 = (cap1 * 64 / 8 + 255) / 256;
    const int gH96_2 = (cap2 * 96 / 8 + 255) / 256;
    const int sb0 = (cap0 + 63) / 64;   // for cin_k
    const int sb1 = (cap1 + 63) / 64;
    const int sb2 = (cap2 + 63) / 64;
    const int g32_0 = (cap0 + 255) / 256;   // MG=2 blocks at L0 (469)
    const int g32_1 = (cap1 + 255) / 256;   // MG=2 at L1 (391)
    const int g32_2 = (cap2 + 127) / 128;   // MG=1 at L2 (123)

    // ---- build phase ----
    hipMemsetAsync(amap0, 0xFF, (size_t)V0 * 4, stream);
    hipMemsetAsync(grid, 0, (size_t)V0 * 4, stream);
    bn_prep<<<3, 256, 0, stream>>>((const float*)d_in[12], (const float*)d_in[13],
                                   (const float*)d_in[14], (const float*)d_in[15],
                                   (const float*)d_in[16], (const float*)d_in[17],
                                   (const float*)d_in[18], (const float*)d_in[19],
                                   (const float*)d_in[20], (const float*)d_in[21], ss);
    prepB32<27, 32, 32><<<(27 * 1 * 2 * 256 + 255) / 256, 256, 0, stream>>>(w0a, wbA);
    prepB32<27, 64, 64><<<(27 * 2 * 4 * 256 + 255) / 256, 256, 0, stream>>>(w1a, wb1);
    prepB32<27, 96, 96><<<(27 * 3 * 6 * 256 + 255) / 256, 256, 0, stream>>>(w2, wb2);
    prepB32<27, 128, 64><<<(27 * 2 * 8 * 256 + 255) / 256, 256, 0, stream>>>(w1post, wbP1);
    prepB32<27, 64, 32><<<(27 * 1 * 4 * 256 + 255) / 256, 256, 0, stream>>>(w0post, wbP0);
    prepB32<8, 32, 64><<<(8 * 2 * 2 * 256 + 255) / 256, 256, 0, stream>>>(wdown0, wbD0);
    prepB32<8, 64, 96><<<(8 * 3 * 4 * 256 + 255) / 256, 256, 0, stream>>>(wdown1, wbD1);
    scatter_mark<<<gN, B, 0, stream>>>(coords, feats, N, grid, amap0);
    count_k<<<nb0, B, 0, stream>>>(amap0, V0, counts);
    scan_k<<<1, 1024, 0, stream>>>(counts, nb0, cnt + 0);
    emit_k<<<nb0, B, 0, stream>>>(amap0, V0, counts, vlist0);
    flag_coarse<50><<<nb1, B, 0, stream>>>(amap0, amap1);
    count_k<<<nb1, B, 0, stream>>>(amap1, V1, counts);
    scan_k<<<1, 1024, 0, stream>>>(counts, nb1, cnt + 1);
    emit_k<<<nb1, B, 0, stream>>>(amap1, V1, counts, vlist1);
    flag_coarse<25><<<nb2, B, 0, stream>>>(amap1, amap2);
    count_k<<<nb2, B, 0, stream>>>(amap2, V2, counts);
    scan_k<<<1, 1024, 0, stream>>>(counts, nb2, cnt + 2);
    emit_k<<<nb2, B, 0, stream>>>(amap2, V2, counts, vlist2);

    // ---- network ----
    cin_k<2, 100><<<sb0, 128, 0, stream>>>(grid, w_in, vlist0, cnt + 0, P1);
    act_h16<<<gH32_0, 256, 0, stream>>>(P1, HA, ss + 0, ss + 32, cnt + 0, 32);
    hipMemsetAsync(HA + (size_t)cap0 * 16, 0, 16 * 4, stream);
    gconv_m32<2, 0, 2, 1, 32, 100><<<dim3(g32_0, 1), 256, 0, stream>>>(
        HA, nullptr, wbA, amap0, vlist0, cnt + 0, cap0, P2);
    act_h16<<<gH32_0, 256, 0, stream>>>(P2, HB, ss + 64, ss + 96, cnt + 0, 32);
    dconv_m32<2, 2, 2, 64, 50><<<dim3(g32_1, 1), 256, 0, stream>>>(
        HB, wbD0, amap0, vlist1, cnt + 1, cap0, Q1);
    act_h16<<<gH64_1, 256, 0, stream>>>(Q1, HC, ss + 128, ss + 192, cnt + 1, 64);
    hipMemsetAsync(HC + (size_t)cap1 * 32, 0, 32 * 4, stream);
    gconv_m32<4, 0, 2, 2, 64, 50><<<dim3(g32_1, 1), 256, 0, stream>>>(
        HC, nullptr, wb1, amap1, vlist1, cnt + 1, cap1, Q2);
    act_h16<<<gH64_1, 256, 0, stream>>>(Q2, HD, ss + 256, ss + 320, cnt + 1, 64);
    dconv_m32<4, 1, 1, 96, 25><<<dim3(g32_2, 3), 256, 0, stream>>>(
        HD, wbD1, amap1, vlist2, cnt + 2, cap1, R1);
    act_h16<<<gH96_2, 256, 0, stream>>>(R1, HE, ss + 384, ss + 480, cnt + 2, 96);
    hipMemsetAsync(HE + (size_t)cap2 * 48, 0, 48 * 4, stream);
    gconv_m32<6, 0, 1, 1, 96, 25><<<dim3(g32_2, 3), 256, 0, stream>>>(
        HE, nullptr, wb2, amap2, vlist2, cnt + 2, cap2, R2);
    act_k<<<gA96, 256, 0, stream>>>(R2, R2, ss + 576, ss + 672, cnt + 2, 96);
    uconv_w<96, 64, 25><<<dim3(sb2, 2), 256, 0, stream>>>(
        R2, wup1, amap1, vlist2, cnt + 2, Q1);
    act_h16<<<gH64_1, 256, 0, stream>>>(Q2, HG1, ss + 768, ss + 896, cnt + 1, 64);
    hipMemsetAsync(HG1 + (size_t)cap1 * 32, 0, 32 * 4, stream);
    act_h16<<<gH64_1, 256, 0, stream>>>(Q1, HG2, ss + 768 + 64, ss + 896 + 64, cnt + 1, 64);
    hipMemsetAsync(HG2 + (size_t)cap1 * 32, 0, 32 * 4, stream);
    gconv_m32<4, 4, 2, 2, 64, 50><<<dim3(g32_1, 1), 256, 0, stream>>>(
        HG1, HG2, wbP1, amap1, vlist1, cnt + 1, cap1, Q2);
    act_k<<<gA64, 256, 0, stream>>>(Q2, Q2, ss + 1024, ss + 1088, cnt + 1, 64);
    uconv_w<64, 32, 50><<<dim3(sb1, 1), 256, 0, stream>>>(
        Q2, wup0, amap0, vlist1, cnt + 1, P1);
    act_h16<<<gH32_0, 256, 0, stream>>>(P2, HI1, ss + 1152, ss + 1216, cnt + 0, 32);
    hipMemsetAsync(HI1 + (size_t)cap0 * 16, 0, 16 * 4, stream);
    act_h16<<<gH32_0, 256, 0, stream>>>(P1, HI2, ss + 1152 + 32, ss + 1216 + 32, cnt + 0, 32);
    hipMemsetAsync(HI2 + (size_t)cap0 * 16, 0, 16 * 4, stream);
    gconv_m32<2, 2, 2, 1, 32, 100><<<dim3(g32_0, 1), 256, 0, stream>>>(
        HI1, HI2, wbP0, amap0, vlist0, cnt + 0, cap0, P2);
    final_k<<<gN, B, 0, stream>>>(coords, P2, amap0, ss + 1280, linW, linb, N, outp);
}

// Round 13
// 515.752 us; speedup vs baseline: 1.1846x; 1.1846x over previous
//
#include <hip/hip_runtime.h>

// ---------------------------------------------------------------------------
// Sparse 3D U-Net forward (MI355X / gfx950).
// All 3x3x3 convs AND strided down-convs = barrier-free implicit GEMM via
// mfma_f32_32x32x16_f16, ONE WAVE PER BLOCK (64 thr) for maximal grid
// parallelism at full arithmetic intensity:
//   wave = 32 slots x (CTILES*32) couts; A-frag = one 16B gathered load/lane
//   (acts [slot][cin] f16, zero row at cap); B-frag = weights pre-packed to
//   fragment order, loaded directly from global (L1/L2-resident, lane-linear).
//   A: row=lane&31, k=(lane>>5)*8+j ; B: col=lane&31, same k map. D: col=
//   lane&31, row=(reg&3)+8*(reg>>2)+4*(lane>>5). Up-convs/cin/final stay f32.
// ---------------------------------------------------------------------------

#define NVOX 100
#define EPSB 1e-4f
typedef unsigned long long u64;
typedef _Float16 h2 __attribute__((ext_vector_type(2)));
typedef _Float16 h8 __attribute__((ext_vector_type(8)));
typedef float f16v __attribute__((ext_vector_type(16)));
#define DEVFN __device__ __forceinline__

// Packed B: wb[((t*CTG + ct)*KCH + kc)*256 + lane*4 + jh] (h2 units):
//   k0 = kc*16 + (lane>>5)*8 + 2*jh ; co = ct*32 + (lane&31)
template<int NTAPS, int CTOT, int COUT>
__global__ __launch_bounds__(256)
void prepB32(const float* __restrict__ w, h2* __restrict__ out)
{
    constexpr int CTG = COUT / 32, KCH = CTOT / 16;
    const int n = NTAPS * CTG * KCH * 256;
    const int idx = blockIdx.x * 256 + threadIdx.x;
    if (idx >= n) return;
    const int jh = idx & 3;
    const int lane = (idx >> 2) & 63;
    int r = idx >> 8;                 // (t*CTG + ct)*KCH + kc
    const int kc = r % KCH; r /= KCH;
    const int ct = r % CTG; const int t = r / CTG;
    const int k0 = kc * 16 + (lane >> 5) * 8 + 2 * jh;
    const int co = ct * 32 + (lane & 31);
    h2 v;
    v[0] = (_Float16)w[((size_t)t * CTOT + k0) * COUT + co];
    v[1] = (_Float16)w[((size_t)t * CTOT + k0 + 1) * COUT + co];
    out[idx] = v;
}

// 3x3x3 SAME submanifold conv, f16 acts, 32x32x16 MFMA, 1-wave blocks.
// grid = (ceil(cap/32), COUT/(CTILES*32)); block = 64.
template<int KC1, int KC2, int CTILES, int COUT, int S>
__global__ __launch_bounds__(64)
void gconv_m32(const h2* __restrict__ inA, const h2* __restrict__ inB,
               const h2* __restrict__ wb,
               const int* __restrict__ amap, const int* __restrict__ vlist,
               const int* __restrict__ cnt, int cap, float* __restrict__ out)
{
    constexpr int KCH = KC1 + KC2;
    constexpr int CTG = COUT / 32;
    const int lane = threadIdx.x;
    const int cntv = *cnt;
    const int wbase = blockIdx.x * 32;
    if (wbase >= cntv) return;
    const int ct0 = blockIdx.y * CTILES;
    const int l31 = lane & 31, ksub = lane >> 5;
    const int slot = wbase + l31;
    const bool on = slot < cntv;
    int X = 0, Y = 0, Z = 0;
    if (on) { const int v = vlist[slot]; X = v % S; const int r = v / S; Y = r % S; Z = r / S; }

    auto calc_ns = [&](int t) -> int {
        int ns = cap;
        if (on) {
            const int dz = t / 9 - 1, dy = (t / 3) % 3 - 1, dx = t % 3 - 1;
            const int nz = Z + dz, ny = Y + dy, nx = X + dx;
            if ((unsigned)nz < (unsigned)S && (unsigned)ny < (unsigned)S &&
                (unsigned)nx < (unsigned)S) {
                const int m = amap[(nz * S + ny) * S + nx];
                if (m >= 0) ns = m;
            }
        }
        return ns;
    };

    f16v acc[CTILES];
#pragma unroll
    for (int c = 0; c < CTILES; ++c) acc[c] = (f16v)(0.f);

    int ns = calc_ns(0);
#pragma unroll 1
    for (int t = 0; t < 27; ++t) {
        const int ns_nxt = (t + 1 < 27) ? calc_ns(t + 1) : cap;
        const h2* __restrict__ wt = wb + ((size_t)t * CTG + ct0) * KCH * 256;
#pragma unroll
        for (int kc = 0; kc < KC1; ++kc) {
            const h8 a = *reinterpret_cast<const h8*>(
                inA + (size_t)ns * (KC1 * 8) + kc * 8 + ksub * 4);
#pragma unroll
            for (int ct = 0; ct < CTILES; ++ct) {
                const h8 b = *reinterpret_cast<const h8*>(
                    wt + ((size_t)ct * KCH + kc) * 256 + lane * 4);
                acc[ct] = __builtin_amdgcn_mfma_f32_32x32x16_f16(a, b, acc[ct], 0, 0, 0);
            }
        }
        if constexpr (KC2 > 0) {
#pragma unroll
            for (int kc = 0; kc < KC2; ++kc) {
                const h8 a = *reinterpret_cast<const h8*>(
                    inB + (size_t)ns * (KC2 * 8) + kc * 8 + ksub * 4);
#pragma unroll
                for (int ct = 0; ct < CTILES; ++ct) {
                    const h8 b = *reinterpret_cast<const h8*>(
                        wt + ((size_t)ct * KCH + KC1 + kc) * 256 + lane * 4);
                    acc[ct] = __builtin_amdgcn_mfma_f32_32x32x16_f16(a, b, acc[ct], 0, 0, 0);
                }
            }
        }
        ns = ns_nxt;
    }
    // D: col=l31, row=(r&3)+8*(r>>2)+4*ksub
#pragma unroll
    for (int ct = 0; ct < CTILES; ++ct)
#pragma unroll
        for (int r = 0; r < 16; ++r) {
            const int row = (r & 3) + 8 * (r >> 2) + 4 * ksub;
            const int srow = wbase + row;
            if (srow < cntv)
                out[(size_t)srow * COUT + (ct0 + ct) * 32 + l31] = acc[ct][r];
        }
}

// 2x2x2 stride-2 down conv, coarse-driven, f16 acts, 32x32x16 MFMA, 1-wave.
template<int KCH, int CTILES, int COUT, int SC>
__global__ __launch_bounds__(64)
void dconv_m32(const h2* __restrict__ in, const h2* __restrict__ wb,
               const int* __restrict__ amap_f, const int* __restrict__ vlist_c,
               const int* __restrict__ cnt_c, int capf, float* __restrict__ out)
{
    constexpr int SF = SC * 2;
    constexpr int CTG = COUT / 32;
    const int lane = threadIdx.x;
    const int cntv = *cnt_c;
    const int wbase = blockIdx.x * 32;
    if (wbase >= cntv) return;
    const int ct0 = blockIdx.y * CTILES;
    const int l31 = lane & 31, ksub = lane >> 5;
    const int slot = wbase + l31;
    const bool on = slot < cntv;
    int X = 0, Y = 0, Z = 0;
    if (on) { const int v = vlist_c[slot]; X = v % SC; const int r = v / SC; Y = r % SC; Z = r / SC; }

    auto calc_ns = [&](int t) -> int {
        int ns = capf;
        if (on) {
            const int fz = 2 * Z + ((t >> 2) & 1);
            const int fy = 2 * Y + ((t >> 1) & 1);
            const int fx = 2 * X + (t & 1);
            const int m = amap_f[(fz * SF + fy) * SF + fx];
            if (m >= 0) ns = m;
        }
        return ns;
    };

    f16v acc[CTILES];
#pragma unroll
    for (int c = 0; c < CTILES; ++c) acc[c] = (f16v)(0.f);

    int ns = calc_ns(0);
#pragma unroll 1
    for (int t = 0; t < 8; ++t) {
        const int ns_nxt = (t + 1 < 8) ? calc_ns(t + 1) : capf;
        const h2* __restrict__ wt = wb + ((size_t)t * CTG + ct0) * KCH * 256;
#pragma unroll
        for (int kc = 0; kc < KCH; ++kc) {
            const h8 a = *reinterpret_cast<const h8*>(
                in + (size_t)ns * (KCH * 8) + kc * 8 + ksub * 4);
#pragma unroll
            for (int ct = 0; ct < CTILES; ++ct) {
                const h8 b = *reinterpret_cast<const h8*>(
                    wt + ((size_t)ct * KCH + kc) * 256 + lane * 4);
                acc[ct] = __builtin_amdgcn_mfma_f32_32x32x16_f16(a, b, acc[ct], 0, 0, 0);
            }
        }
        ns = ns_nxt;
    }
#pragma unroll
    for (int ct = 0; ct < CTILES; ++ct)
#pragma unroll
        for (int r = 0; r < 16; ++r) {
            const int row = (r & 3) + 8 * (r >> 2) + 4 * ksub;
            const int srow = wbase + row;
            if (srow < cntv)
                out[(size_t)srow * COUT + (ct0 + ct) * 32 + l31] = acc[ct][r];
        }
}

// Fused bnrelu + f32->f16 pack: dst[slot][C/2 h2] over cnt*C floats (C%8==0).
__global__ __launch_bounds__(256)
void act_h16(const float* __restrict__ src, h2* __restrict__ dst,
             const float* __restrict__ sc, const float* __restrict__ sh,
             const int* __restrict__ cnt, int C)
{
    const int f = (blockIdx.x * 256 + threadIdx.x) * 8;
    if (f >= (*cnt) * C) return;
    const int c0 = f % C;
    const float4 v0 = *reinterpret_cast<const float4*>(src + f);
    const float4 v1 = *reinterpret_cast<const float4*>(src + f + 4);
    const float r[8] = {
        fmaxf(fmaf(v0.x, sc[c0 + 0], sh[c0 + 0]), 0.f),
        fmaxf(fmaf(v0.y, sc[c0 + 1], sh[c0 + 1]), 0.f),
        fmaxf(fmaf(v0.z, sc[c0 + 2], sh[c0 + 2]), 0.f),
        fmaxf(fmaf(v0.w, sc[c0 + 3], sh[c0 + 3]), 0.f),
        fmaxf(fmaf(v1.x, sc[c0 + 4], sh[c0 + 4]), 0.f),
        fmaxf(fmaf(v1.y, sc[c0 + 5], sh[c0 + 5]), 0.f),
        fmaxf(fmaf(v1.z, sc[c0 + 6], sh[c0 + 6]), 0.f),
        fmaxf(fmaf(v1.w, sc[c0 + 7], sh[c0 + 7]), 0.f)};
    union { float4 v; h2 h[4]; } o;
#pragma unroll
    for (int k = 0; k < 4; ++k) {
        h2 p; p[0] = (_Float16)r[2 * k]; p[1] = (_Float16)r[2 * k + 1];
        o.h[k] = p;
    }
    *reinterpret_cast<float4*>(dst + f / 2) = o.v;
}

// ---------------- f32 machinery for up convs (LDS-staged, R6) ----------------

template<int CTOT, int COUT>
DEVFN void stage_tap(const float* __restrict__ wtap, int cg32,
                     float* __restrict__ lbuf, int wid, int lane)
{
    constexpr int IPW = CTOT / 32;
#pragma unroll
    for (int i = 0; i < IPW; ++i) {
        const int chunk = wid * IPW + i;
        const int f4i = chunk * 64 + lane;
        const int ci = f4i >> 3, sub = f4i & 7;
        const float* g = wtap + ci * COUT + cg32 + sub * 4;
        __builtin_amdgcn_global_load_lds(
            (const __attribute__((address_space(1))) void*)g,
            (__attribute__((address_space(3))) void*)(lbuf + chunk * 256),
            16, 0, 0);
    }
}

template<int CIN>
DEVFN void dorow8(const float* __restrict__ row, const float* __restrict__ wl,
                  float (&acc)[8])
{
#pragma unroll 4
    for (int c0 = 0; c0 < CIN; c0 += 4) {
        const float4 a = *reinterpret_cast<const float4*>(row + c0);
        const float av[4] = {a.x, a.y, a.z, a.w};
#pragma unroll
        for (int j = 0; j < 4; ++j) {
            const float4 w0 = *reinterpret_cast<const float4*>(wl + (c0 + j) * 32);
            const float4 w1 = *reinterpret_cast<const float4*>(wl + (c0 + j) * 32 + 4);
            acc[0] = fmaf(av[j], w0.x, acc[0]);
            acc[1] = fmaf(av[j], w0.y, acc[1]);
            acc[2] = fmaf(av[j], w0.z, acc[2]);
            acc[3] = fmaf(av[j], w0.w, acc[3]);
            acc[4] = fmaf(av[j], w1.x, acc[4]);
            acc[5] = fmaf(av[j], w1.y, acc[5]);
            acc[6] = fmaf(av[j], w1.z, acc[6]);
            acc[7] = fmaf(av[j], w1.w, acc[7]);
        }
    }
}

template<int CIN, int COUT, int SC>
__global__ __launch_bounds__(256)
void uconv_w(const float* __restrict__ in, const float* __restrict__ w,
             const int* __restrict__ amap_f, const int* __restrict__ vlist_c,
             const int* __restrict__ cnt_c, float* __restrict__ out)
{
    constexpr int SF = SC * 2;
    __shared__ float lw[2][CIN * 32];
    const int tid = threadIdx.x, lane = tid & 63, wid = tid >> 6;
    const int cntv = *cnt_c;
    if (blockIdx.x * 64 >= cntv) return;
    const int slot = blockIdx.x * 64 + lane;
    const int cg32 = blockIdx.y * 32;
    const bool on = slot < cntv;
    int X = 0, Y = 0, Z = 0;
    if (on) { const int v = vlist_c[slot]; X = v % SC; const int r = v / SC; Y = r % SC; Z = r / SC; }
    stage_tap<CIN, COUT>(w + (size_t)7 * CIN * COUT, cg32, lw[0], wid, lane);
    __syncthreads();
#pragma unroll 1
    for (int t = 0; t < 8; ++t) {
        if (t + 1 < 8)
            stage_tap<CIN, COUT>(w + (size_t)(6 - t) * CIN * COUT, cg32,
                                 lw[(t + 1) & 1], wid, lane);
        int cs = -1;
        if (on) {
            const int fz = 2 * Z + ((t >> 2) & 1);
            const int fy = 2 * Y + ((t >> 1) & 1);
            const int fx = 2 * X + (t & 1);
            cs = amap_f[(fz * SF + fy) * SF + fx];
        }
        if (cs >= 0) {
            float acc[8];
#pragma unroll
            for (int q = 0; q < 8; ++q) acc[q] = 0.f;
            dorow8<CIN>(in + (size_t)slot * CIN, &lw[t & 1][wid * 8], acc);
            float* __restrict__ op = out + (size_t)cs * COUT + cg32 + wid * 8;
            *reinterpret_cast<float4*>(op) = make_float4(acc[0], acc[1], acc[2], acc[3]);
            *reinterpret_cast<float4*>(op + 4) = make_float4(acc[4], acc[5], acc[6], acc[7]);
        }
        __syncthreads();
    }
}

// First conv: dense 1-channel grid -> 32ch sparse.
template<int OSPLIT, int S>
__global__ __launch_bounds__(64 * OSPLIT)
void cin_k(const float* __restrict__ grid, const float* __restrict__ w,
           const int* __restrict__ vlist, const int* __restrict__ cnt,
           float* __restrict__ out)
{
    constexpr int OW = 32 / OSPLIT;
    const int wOff = __builtin_amdgcn_readfirstlane(threadIdx.x >> 6) * OW;
    const int slot = blockIdx.x * 64 + (threadIdx.x & 63);
    if (slot >= *cnt) return;
    const int v = vlist[slot];
    const int x = v % S;
    const int rem = v / S;
    const int y = rem % S;
    const int z = rem / S;
    float acc[OW];
#pragma unroll
    for (int c = 0; c < OW; ++c) acc[c] = 0.f;
#pragma unroll
    for (int t = 0; t < 27; ++t) {
        const int dz = t / 9 - 1, dy = (t / 3) % 3 - 1, dx = t % 3 - 1;
        const int nz = z + dz, ny = y + dy, nx = x + dx;
        if ((unsigned)nz >= (unsigned)S || (unsigned)ny >= (unsigned)S ||
            (unsigned)nx >= (unsigned)S) continue;
        const float val = grid[(nz * S + ny) * S + nx];
        const float* __restrict__ wp = w + t * 32 + wOff;
#pragma unroll
        for (int c = 0; c < OW; ++c) acc[c] = fmaf(val, wp[c], acc[c]);
    }
    float* __restrict__ op = out + (size_t)slot * 32 + wOff;
#pragma unroll
    for (int c = 0; c < OW; ++c) op[c] = acc[c];
}

// Elementwise bnrelu (f32 out).
__global__ __launch_bounds__(256)
void act_k(const float* __restrict__ src, float* __restrict__ dst,
           const float* __restrict__ sc, const float* __restrict__ sh,
           const int* __restrict__ cnt, int C)
{
    const int f = (blockIdx.x * 256 + threadIdx.x) * 4;
    if (f >= (*cnt) * C) return;
    const int c0 = f % C;
    const float4 v = *reinterpret_cast<const float4*>(src + f);
    float4 o;
    o.x = fmaxf(fmaf(v.x, sc[c0 + 0], sh[c0 + 0]), 0.f);
    o.y = fmaxf(fmaf(v.y, sc[c0 + 1], sh[c0 + 1]), 0.f);
    o.z = fmaxf(fmaf(v.z, sc[c0 + 2], sh[c0 + 2]), 0.f);
    o.w = fmaxf(fmaf(v.w, sc[c0 + 3], sh[c0 + 3]), 0.f);
    *reinterpret_cast<float4*>(dst + f) = o;
}

// Final: bnrelu(y0, bnJ) then 32->3 linear per point.
__global__ __launch_bounds__(256)
void final_k(const int* __restrict__ coords, const float* __restrict__ y0,
             const int* __restrict__ amap0, const float* __restrict__ ssJ,
             const float* __restrict__ linW, const float* __restrict__ linb,
             int N, float* __restrict__ outp)
{
    const int n = blockIdx.x * blockDim.x + threadIdx.x;
    if (n >= N) return;
    const int i = coords[3 * n + 0];
    const int j = coords[3 * n + 1];
    const int k = coords[3 * n + 2];
    const int v = (i * NVOX + j) * NVOX + k;
    const int s = amap0[v];
    float a0 = linb[0], a1 = linb[1], a2 = linb[2];
    if (s >= 0) {
        const float* __restrict__ row = y0 + (size_t)s * 32;
#pragma unroll
        for (int c = 0; c < 32; ++c) {
            const float t = fmaxf(fmaf(row[c], ssJ[c], ssJ[32 + c]), 0.f);
            a0 = fmaf(t, linW[c * 3 + 0], a0);
            a1 = fmaf(t, linW[c * 3 + 1], a1);
            a2 = fmaf(t, linW[c * 3 + 2], a2);
        }
    }
    outp[3 * n + 0] = a0;
    outp[3 * n + 1] = a1;
    outp[3 * n + 2] = a2;
}

// Precompute per-channel scale/shift for all 10 BN layers.
__global__ void bn_prep(const float* __restrict__ A, const float* __restrict__ B,
                        const float* __restrict__ C, const float* __restrict__ D,
                        const float* __restrict__ E, const float* __restrict__ F,
                        const float* __restrict__ G, const float* __restrict__ H,
                        const float* __restrict__ I, const float* __restrict__ J,
                        float* __restrict__ ss)
{
    const float* bp[10] = {A, B, C, D, E, F, G, H, I, J};
    const int CH[10] = {32, 32, 64, 64, 96, 96, 128, 64, 64, 32};
    int idx = blockIdx.x * blockDim.x + threadIdx.x;
    if (idx >= 672) return;
    int l = 0, base = 0, off2 = 0;
    while (idx >= base + CH[l]) { base += CH[l]; off2 += 2 * CH[l]; ++l; }
    const int c = idx - base;
    const float* bn = bp[l];
    const int Cc = CH[l];
    const float g = bn[c], b = bn[Cc + c], mu = bn[2 * Cc + c], var = bn[3 * Cc + c];
    const float sc = g * rsqrtf(var + EPSB);
    ss[off2 + c] = sc;
    ss[off2 + Cc + c] = b - mu * sc;
}

__global__ __launch_bounds__(256)
void scatter_mark(const int* __restrict__ coords, const float* __restrict__ feats,
                  int N, float* __restrict__ grid, int* __restrict__ amap0)
{
    const int n = blockIdx.x * blockDim.x + threadIdx.x;
    if (n >= N) return;
    const int i = coords[3 * n + 0];
    const int j = coords[3 * n + 1];
    const int k = coords[3 * n + 2];
    const int v = (i * NVOX + j) * NVOX + k;
    atomicAdd(&grid[v], feats[n]);
    amap0[v] = -2;
}

template<int SC>
__global__ __launch_bounds__(256)
void flag_coarse(const int* __restrict__ amap_f, int* __restrict__ amap_c)
{
    constexpr int SF = SC * 2;
    const int v = blockIdx.x * blockDim.x + threadIdx.x;
    if (v >= SC * SC * SC) return;
    const int x = v % SC;
    const int rem = v / SC;
    const int y = rem % SC;
    const int z = rem / SC;
    bool any = false;
#pragma unroll
    for (int t = 0; t < 8; ++t) {
        const int fz = 2 * z + ((t >> 2) & 1);
        const int fy = 2 * y + ((t >> 1) & 1);
        const int fx = 2 * x + (t & 1);
        if (amap_f[(fz * SF + fy) * SF + fx] >= 0) any = true;
    }
    amap_c[v] = any ? -2 : -1;
}

// ---- deterministic raster-order compaction: count -> scan -> emit ----
__global__ __launch_bounds__(256)
void count_k(const int* __restrict__ flags, int V, int* __restrict__ counts)
{
    const int v = blockIdx.x * 256 + threadIdx.x;
    const bool act = (v < V) && (flags[v] == -2);
    const u64 m = __ballot(act);
    __shared__ int c[4];
    const int wid = threadIdx.x >> 6;
    if ((threadIdx.x & 63) == 0) c[wid] = __popcll(m);
    __syncthreads();
    if (threadIdx.x == 0) counts[blockIdx.x] = c[0] + c[1] + c[2] + c[3];
}

__global__ __launch_bounds__(1024)
void scan_k(int* __restrict__ counts, int nb, int* __restrict__ total)
{
    __shared__ int sums[1024];
    const int t = threadIdx.x;
    int v[4];
    int s = 0;
#pragma unroll
    for (int i = 0; i < 4; ++i) {
        const int idx = t * 4 + i;
        v[i] = (idx < nb) ? counts[idx] : 0;
        s += v[i];
    }
    sums[t] = s;
    __syncthreads();
    for (int d = 1; d < 1024; d <<= 1) {
        const int add = (t >= d) ? sums[t - d] : 0;
        __syncthreads();
        sums[t] += add;
        __syncthreads();
    }
    int base = (t > 0) ? sums[t - 1] : 0;
#pragma unroll
    for (int i = 0; i < 4; ++i) {
        const int idx = t * 4 + i;
        if (idx < nb) counts[idx] = base;
        base += v[i];
    }
    if (t == 1023) *total = sums[1023];
}

__global__ __launch_bounds__(256)
void emit_k(int* __restrict__ amap, int V, const int* __restrict__ offsets,
            int* __restrict__ vlist)
{
    const int v = blockIdx.x * 256 + threadIdx.x;
    const bool act = (v < V) && (amap[v] == -2);
    const u64 m = __ballot(act);
    __shared__ int wbase[4];
    const int wid = threadIdx.x >> 6;
    const int lane = threadIdx.x & 63;
    if (lane == 0) wbase[wid] = __popcll(m);
    __syncthreads();
    if (threadIdx.x == 0) {
        int s = 0;
#pragma unroll
        for (int i = 0; i < 4; ++i) { const int t = wbase[i]; wbase[i] = s; s += t; }
    }
    __syncthreads();
    if (act) {
        const int slot = offsets[blockIdx.x] + wbase[wid] +
                         __popcll(m & ((1ull << lane) - 1ull));
        amap[v] = slot;
        vlist[slot] = v;
    }
}

extern "C" void kernel_launch(void* const* d_in, const int* in_sizes, int n_in,
                              void* d_out, int out_size, void* d_ws, size_t ws_size,
                              hipStream_t stream) {
    const int*   coords = (const int*)d_in[0];
    const float* feats  = (const float*)d_in[1];
    const float* w_in   = (const float*)d_in[2];
    const float* w0a    = (const float*)d_in[3];
    const float* wdown0 = (const float*)d_in[4];
    const float* w1a    = (const float*)d_in[5];
    const float* wdown1 = (const float*)d_in[6];
    const float* w2     = (const float*)d_in[7];
    const float* wup1   = (const float*)d_in[8];
    const float* w1post = (const float*)d_in[9];
    const float* wup0   = (const float*)d_in[10];
    const float* w0post = (const float*)d_in[11];
    const float* linW = (const float*)d_in[22];
    const float* linb = (const float*)d_in[23];
    float* outp = (float*)d_out;

    const int N = in_sizes[1];            // 120000 points
    const int V0 = NVOX * NVOX * NVOX;
    const int V1 = 50 * 50 * 50;
    const int V2 = 25 * 25 * 25;
    const int cap0 = N;
    const int cap1 = 100000;
    const int cap2 = V2;

    char* ws = (char*)d_ws;
    size_t off = 0;
    auto alloc = [&](size_t bytes) -> void* {
        void* p = ws + off;
        off += (bytes + 255) & ~(size_t)255;
        return p;
    };
    int*   amap0  = (int*)alloc((size_t)V0 * 4);
    int*   vlist0 = (int*)alloc((size_t)cap0 * 4);
    int*   amap1  = (int*)alloc((size_t)V1 * 4);
    int*   vlist1 = (int*)alloc((size_t)cap1 * 4);
    int*   amap2  = (int*)alloc((size_t)V2 * 4);
    int*   vlist2 = (int*)alloc((size_t)cap2 * 4);
    int*   cnt    = (int*)alloc(3 * 4);
    int*   counts = (int*)alloc(4096 * 4);
    float* ss     = (float*)alloc(1344 * 4);
    float* grid   = (float*)alloc((size_t)V0 * 4);
    float* P1 = (float*)alloc((size_t)cap0 * 32 * 4);  // x -> HG2 -> u0
    float* P2 = (float*)alloc((size_t)cap0 * 32 * 4);  // x0 -> y0
    float* P3 = (float*)alloc((size_t)cap0 * 32 * 4);  // HA / HB / HI1
    float* Q1 = (float*)alloc((size_t)cap1 * 64 * 4);  // d0 -> HE -> u1
    float* Q2 = (float*)alloc((size_t)cap1 * 64 * 4);  // x1 -> y1/actH -> HI2
    float* Q3 = (float*)alloc((size_t)cap1 * 64 * 4);  // HC / HD / HG1
    float* R1 = (float*)alloc((size_t)cap2 * 96 * 4);  // d1
    float* R2 = (float*)alloc((size_t)cap2 * 96 * 4);  // x2/actF
    h2* wbA  = (h2*)alloc((size_t)27 * 1 * 2 * 256 * 4);   // w0a packed B32
    h2* wb1  = (h2*)alloc((size_t)27 * 2 * 4 * 256 * 4);   // w1a
    h2* wb2  = (h2*)alloc((size_t)27 * 3 * 6 * 256 * 4);   // w2
    h2* wbP1 = (h2*)alloc((size_t)27 * 2 * 8 * 256 * 4);   // w1post
    h2* wbP0 = (h2*)alloc((size_t)27 * 1 * 4 * 256 * 4);   // w0post
    h2* wbD0 = (h2*)alloc((size_t)8 * 2 * 2 * 256 * 4);    // wdown0
    h2* wbD1 = (h2*)alloc((size_t)8 * 3 * 4 * 256 * 4);    // wdown1
    if (off > ws_size) return;

    // f16 activation aliases (sequentially reused dead f32 buffers)
    h2* HA  = (h2*)P3;   // actA  (16 h2/row)
    h2* HB  = (h2*)P3;   // actB  (16) — reuses HA geometry + zero row
    h2* HC  = (h2*)Q3;   // actC  (32)
    h2* HD  = (h2*)Q3;   // actD  (32) — reuses HC geometry + zero row
    h2* HE  = (h2*)Q1;   // actE  (48)
    h2* HG1 = (h2*)Q3;   // actG1 (32)
    h2* HG2 = (h2*)P1;   // actG2 (32)
    h2* HI1 = (h2*)P3;   // actI1 (16)
    h2* HI2 = (h2*)Q2;   // actI2 (16)

    const int B = 256;
    const int gN  = (N + B - 1) / B;
    const int nb0 = (V0 + B - 1) / B;
    const int nb1 = (V1 + B - 1) / B;
    const int nb2 = (V2 + B - 1) / B;
    const int gA64 = (cap1 * 64 / 4 + 255) / 256;
    const int gA96 = (cap2 * 96 / 4 + 255) / 256;
    const int gH32_0 = (cap0 * 32 / 8 + 255) / 256;
    const int gH64_1 = (cap1 * 64 / 8 + 255) / 256;
    const int gH96_2 = (cap2 * 96 / 8 + 255) / 256;
    const int sb0 = (cap0 + 63) / 64;   // for cin_k
    const int sb1 = (cap1 + 63) / 64;
    const int sb2 = (cap2 + 63) / 64;
    const int g1w_0 = (cap0 + 31) / 32;   // 3750 one-wave blocks at L0
    const int g1w_1 = (cap1 + 31) / 32;   // 3125 at L1
    const int g1w_2 = (cap2 + 31) / 32;   // 489 at L2

    // ---- build phase ----
    hipMemsetAsync(amap0, 0xFF, (size_t)V0 * 4, stream);
    hipMemsetAsync(grid, 0, (size_t)V0 * 4, stream);
    bn_prep<<<3, 256, 0, stream>>>((const float*)d_in[12], (const float*)d_in[13],
                                   (const float*)d_in[14], (const float*)d_in[15],
                                   (const float*)d_in[16], (const float*)d_in[17],
                                   (const float*)d_in[18], (const float*)d_in[19],
                                   (const float*)d_in[20], (const float*)d_in[21], ss);
    prepB32<27, 32, 32><<<(27 * 1 * 2 * 256 + 255) / 256, 256, 0, stream>>>(w0a, wbA);
    prepB32<27, 64, 64><<<(27 * 2 * 4 * 256 + 255) / 256, 256, 0, stream>>>(w1a, wb1);
    prepB32<27, 96, 96><<<(27 * 3 * 6 * 256 + 255) / 256, 256, 0, stream>>>(w2, wb2);
    prepB32<27, 128, 64><<<(27 * 2 * 8 * 256 + 255) / 256, 256, 0, stream>>>(w1post, wbP1);
    prepB32<27, 64, 32><<<(27 * 1 * 4 * 256 + 255) / 256, 256, 0, stream>>>(w0post, wbP0);
    prepB32<8, 32, 64><<<(8 * 2 * 2 * 256 + 255) / 256, 256, 0, stream>>>(wdown0, wbD0);
    prepB32<8, 64, 96><<<(8 * 3 * 4 * 256 + 255) / 256, 256, 0, stream>>>(wdown1, wbD1);
    scatter_mark<<<gN, B, 0, stream>>>(coords, feats, N, grid, amap0);
    count_k<<<nb0, B, 0, stream>>>(amap0, V0, counts);
    scan_k<<<1, 1024, 0, stream>>>(counts, nb0, cnt + 0);
    emit_k<<<nb0, B, 0, stream>>>(amap0, V0, counts, vlist0);
    flag_coarse<50><<<nb1, B, 0, stream>>>(amap0, amap1);
    count_k<<<nb1, B, 0, stream>>>(amap1, V1, counts);
    scan_k<<<1, 1024, 0, stream>>>(counts, nb1, cnt + 1);
    emit_k<<<nb1, B, 0, stream>>>(amap1, V1, counts, vlist1);
    flag_coarse<25><<<nb2, B, 0, stream>>>(amap1, amap2);
    count_k<<<nb2, B, 0, stream>>>(amap2, V2, counts);
    scan_k<<<1, 1024, 0, stream>>>(counts, nb2, cnt + 2);
    emit_k<<<nb2, B, 0, stream>>>(amap2, V2, counts, vlist2);

    // ---- network ----
    cin_k<2, 100><<<sb0, 128, 0, stream>>>(grid, w_in, vlist0, cnt + 0, P1);
    act_h16<<<gH32_0, 256, 0, stream>>>(P1, HA, ss + 0, ss + 32, cnt + 0, 32);
    hipMemsetAsync(HA + (size_t)cap0 * 16, 0, 16 * 4, stream);
    gconv_m32<2, 0, 1, 32, 100><<<dim3(g1w_0, 1), 64, 0, stream>>>(
        HA, nullptr, wbA, amap0, vlist0, cnt + 0, cap0, P2);
    act_h16<<<gH32_0, 256, 0, stream>>>(P2, HB, ss + 64, ss + 96, cnt + 0, 32);
    dconv_m32<2, 2, 64, 50><<<dim3(g1w_1, 1), 64, 0, stream>>>(
        HB, wbD0, amap0, vlist1, cnt + 1, cap0, Q1);
    act_h16<<<gH64_1, 256, 0, stream>>>(Q1, HC, ss + 128, ss + 192, cnt + 1, 64);
    hipMemsetAsync(HC + (size_t)cap1 * 32, 0, 32 * 4, stream);
    gconv_m32<4, 0, 2, 64, 50><<<dim3(g1w_1, 1), 64, 0, stream>>>(
        HC, nullptr, wb1, amap1, vlist1, cnt + 1, cap1, Q2);
    act_h16<<<gH64_1, 256, 0, stream>>>(Q2, HD, ss + 256, ss + 320, cnt + 1, 64);
    dconv_m32<4, 1, 96, 25><<<dim3(g1w_2, 3), 64, 0, stream>>>(
        HD, wbD1, amap1, vlist2, cnt + 2, cap1, R1);
    act_h16<<<gH96_2, 256, 0, stream>>>(R1, HE, ss + 384, ss + 480, cnt + 2, 96);
    hipMemsetAsync(HE + (size_t)cap2 * 48, 0, 48 * 4, stream);
    gconv_m32<6, 0, 1, 96, 25><<<dim3(g1w_2, 3), 64, 0, stream>>>(
        HE, nullptr, wb2, amap2, vlist2, cnt + 2, cap2, R2);
    act_k<<<gA96, 256, 0, stream>>>(R2, R2, ss + 576, ss + 672, cnt + 2, 96);
    uconv_w<96, 64, 25><<<dim3(sb2, 2), 256, 0, stream>>>(
        R2, wup1, amap1, vlist2, cnt + 2, Q1);
    act_h16<<<gH64_1, 256, 0, stream>>>(Q2, HG1, ss + 768, ss + 896, cnt + 1, 64);
    hipMemsetAsync(HG1 + (size_t)cap1 * 32, 0, 32 * 4, stream);
    act_h16<<<gH64_1, 256, 0, stream>>>(Q1, HG2, ss + 768 + 64, ss + 896 + 64, cnt + 1, 64);
    hipMemsetAsync(HG2 + (size_t)cap1 * 32, 0, 32 * 4, stream);
    gconv_m32<4, 4, 2, 64, 50><<<dim3(g1w_1, 1), 64, 0, stream>>>(
        HG1, HG2, wbP1, amap1, vlist1, cnt + 1, cap1, Q2);
    act_k<<<gA64, 256, 0, stream>>>(Q2, Q2, ss + 1024, ss + 1088, cnt + 1, 64);
    uconv_w<64, 32, 50><<<dim3(sb1, 1), 256, 0, stream>>>(
        Q2, wup0, amap0, vlist1, cnt + 1, P1);
    act_h16<<<gH32_0, 256, 0, stream>>>(P2, HI1, ss + 1152, ss + 1216, cnt + 0, 32);
    hipMemsetAsync(HI1 + (size_t)cap0 * 16, 0, 16 * 4, stream);
    act_h16<<<gH32_0, 256, 0, stream>>>(P1, HI2, ss + 1152 + 32, ss + 1216 + 32, cnt + 0, 32);
    hipMemsetAsync(HI2 + (size_t)cap0 * 16, 0, 16 * 4, stream);
    gconv_m32<2, 2, 1, 32, 100><<<dim3(g1w_0, 1), 64, 0, stream>>>(
        HI1, HI2, wbP0, amap0, vlist0, cnt + 0, cap0, P2);
    final_k<<<gN, B, 0, stream>>>(coords, P2, amap0, ss + 1280, linW, linb, N, outp);
}